// Round 1
// 1182.425 us; speedup vs baseline: 1.1289x; 1.1289x over previous
//
#include <hip/hip_runtime.h>

// Round 1: fuse qproj+attn (kills 256MB q round-trip + 160MB cold raw/time re-read),
// float4-ize the whole attn phase via a float4 lane<->col mapping, and pre-swizzle
// Wq into MFMA fragment order so GEMM B-loads are contiguous 1KB/wave.

#define NROWS 65536
#define DDIM  512
#define EDIM  256
#define TDIM  128
#define KTOT  896      // D+E+T
#define MT    32       // rows per block
#define APAD  904      // 896 + 8 bf16 pad -> 2-way LDS bank alias (free)
#define KS    28       // KTOT/32 k-steps

using bf16x8 = __attribute__((ext_vector_type(8))) short;
using f32x4  = __attribute__((ext_vector_type(4))) float;

static __device__ __forceinline__ unsigned short f2bf(float f) {
    unsigned int u = __float_as_uint(f);
    return (unsigned short)((u + 0x7fffu + ((u >> 16) & 1u)) >> 16);  // RNE
}
static __device__ __forceinline__ float clampf(float x, float lo, float hi) {
    return fminf(fmaxf(x, lo), hi);
}
static __device__ __forceinline__ float wred_sum(float v) {
    #pragma unroll
    for (int m = 32; m > 0; m >>= 1) v += __shfl_xor(v, m, 64);
    return v;
}
static __device__ __forceinline__ float tanh_fast(float x) {
    x = clampf(x, -15.f, 15.f);
    float e = __expf(2.f * x);
    return (e - 1.f) / (e + 1.f);
}

// ---------------- kernel 0: Wq fp32 -> bf16, swizzled to MFMA fragment order ------
// elem[((ks*32 + ntile)*64 + l)*8 + j] = W[ntile*16 + (l&15)][ks*32 + (l>>4)*8 + j]
// so in the GEMM each wave's b-fragment load is one contiguous 1KB global_load_dwordx4.
__global__ void k_conv_wq(const float* __restrict__ wq, unsigned short* __restrict__ o) {
    int t = blockIdx.x * 256 + threadIdx.x;        // 224*256 = 57344 = 28*32*64
    int l = t & 63, rest = t >> 6;
    int ntile = rest & 31, ks = rest >> 5;
    const float* src = wq + (size_t)(ntile * 16 + (l & 15)) * KTOT + ks * 32 + (l >> 4) * 8;
    f32x4 v0 = ((const f32x4*)src)[0];
    f32x4 v1 = ((const f32x4*)src)[1];
    union { bf16x8 v; unsigned short u[8]; } r;
    #pragma unroll
    for (int j = 0; j < 4; ++j) { r.u[j] = f2bf(v0[j]); r.u[4 + j] = f2bf(v1[j]); }
    ((bf16x8*)o)[t] = r.v;
}

// ---------------- fused kernel: qproj GEMM + LN + tanh + attn + gate + final LN ---
// 256 thr = 4 waves; block does 32 rows end-to-end. 64KB LDS union -> 2 blocks/CU.
__global__ __launch_bounds__(256, 2) void k_fused(
    const float* __restrict__ raw, const float* __restrict__ edge,
    const float* __restrict__ timee, const unsigned short* __restrict__ wqs,
    const float* __restrict__ bq, const float* __restrict__ wg,
    const float* __restrict__ bg, const float* __restrict__ gamma,
    const float* __restrict__ beta, const float* __restrict__ prot,
    const float* __restrict__ temperature, float* __restrict__ out)
{
    __shared__ union {
        unsigned short a[MT * APAD];       // 57856 B  A-stage (bf16)
        float          c[MT * DDIM];       // 65536 B  C-tile (fp32)
        f32x4          c4[MT * DDIM / 4];  // same bytes, forces 16B align
    } sm;

    const int tid = threadIdx.x;
    const int R0  = blockIdx.x * MT;

    // ---- stage A = clamp(concat(raw,edge,time), +-50) as bf16 into LDS ----
    #pragma unroll
    for (int i = 0; i < 16; ++i) {                    // raw: 4096 float4
        int idx = i * 256 + tid;
        int row = idx >> 7, c4i = idx & 127;
        float4 v = ((const float4*)(raw + (size_t)(R0 + row) * DDIM))[c4i];
        unsigned int lo = (unsigned)f2bf(clampf(v.x, -50.f, 50.f)) |
                          ((unsigned)f2bf(clampf(v.y, -50.f, 50.f)) << 16);
        unsigned int hi = (unsigned)f2bf(clampf(v.z, -50.f, 50.f)) |
                          ((unsigned)f2bf(clampf(v.w, -50.f, 50.f)) << 16);
        *(uint2*)(&sm.a[row * APAD + c4i * 4]) = make_uint2(lo, hi);
    }
    #pragma unroll
    for (int i = 0; i < 8; ++i) {                     // edge: 2048 float4
        int idx = i * 256 + tid;
        int row = idx >> 6, c4i = idx & 63;
        float4 v = ((const float4*)(edge + (size_t)(R0 + row) * EDIM))[c4i];
        unsigned int lo = (unsigned)f2bf(clampf(v.x, -50.f, 50.f)) |
                          ((unsigned)f2bf(clampf(v.y, -50.f, 50.f)) << 16);
        unsigned int hi = (unsigned)f2bf(clampf(v.z, -50.f, 50.f)) |
                          ((unsigned)f2bf(clampf(v.w, -50.f, 50.f)) << 16);
        *(uint2*)(&sm.a[row * APAD + DDIM + c4i * 4]) = make_uint2(lo, hi);
    }
    #pragma unroll
    for (int i = 0; i < 4; ++i) {                     // time: 1024 float4
        int idx = i * 256 + tid;
        int row = idx >> 5, c4i = idx & 31;
        float4 v = ((const float4*)(timee + (size_t)(R0 + row) * TDIM))[c4i];
        unsigned int lo = (unsigned)f2bf(clampf(v.x, -50.f, 50.f)) |
                          ((unsigned)f2bf(clampf(v.y, -50.f, 50.f)) << 16);
        unsigned int hi = (unsigned)f2bf(clampf(v.z, -50.f, 50.f)) |
                          ((unsigned)f2bf(clampf(v.w, -50.f, 50.f)) << 16);
        *(uint2*)(&sm.a[row * APAD + DDIM + EDIM + c4i * 4]) = make_uint2(lo, hi);
    }
    __syncthreads();

    // ---- MFMA GEMM: C[32x512] = A[32x896] @ Wq^T (B pre-swizzled, coalesced) ----
    const int w = tid >> 6, l = tid & 63, mlo = l & 15, quad = l >> 4;
    f32x4 acc[2][8];
    #pragma unroll
    for (int rt = 0; rt < 2; ++rt)
        #pragma unroll
        for (int c = 0; c < 8; ++c) acc[rt][c] = (f32x4){0.f, 0.f, 0.f, 0.f};

    const unsigned short* abase0 = &sm.a[ mlo       * APAD + quad * 8];
    const unsigned short* abase1 = &sm.a[(16 + mlo) * APAD + quad * 8];
    const unsigned short* bptr   = wqs + ((size_t)(w * 8) * 64 + l) * 8;

    for (int ks = 0; ks < KS; ++ks) {
        bf16x8 a0 = *(const bf16x8*)(abase0 + ks * 32);
        bf16x8 a1 = *(const bf16x8*)(abase1 + ks * 32);
        bf16x8 bb[8];
        #pragma unroll
        for (int c = 0; c < 8; ++c) bb[c] = *(const bf16x8*)(bptr + c * 512);
        #pragma unroll
        for (int c = 0; c < 8; ++c) {
            acc[0][c] = __builtin_amdgcn_mfma_f32_16x16x32_bf16(a0, bb[c], acc[0][c], 0, 0, 0);
            acc[1][c] = __builtin_amdgcn_mfma_f32_16x16x32_bf16(a1, bb[c], acc[1][c], 0, 0, 0);
        }
        bptr += 32 * 64 * 8;   // next k-step slab
    }

    __syncthreads();   // all waves done reading sm.a before the union flips to C
    #pragma unroll
    for (int rt = 0; rt < 2; ++rt)
        #pragma unroll
        for (int c = 0; c < 8; ++c)
            #pragma unroll
            for (int r2 = 0; r2 < 4; ++r2)
                sm.c[(rt * 16 + quad * 4 + r2) * DDIM + w * 128 + c * 16 + mlo] = acc[rt][c][r2];
    __syncthreads();

    // ---- block constants in float4 mapping: lane l owns cols 4*(l+64*jj)+0..3 ----
    f32x4 bq4[2], g4[2], b4[2], wgr4[2], wgc4[2];
    #pragma unroll
    for (int jj = 0; jj < 2; ++jj) {
        bq4[jj]  = ((const f32x4*)bq)[l + 64 * jj];
        g4[jj]   = ((const f32x4*)gamma)[l + 64 * jj];
        b4[jj]   = ((const f32x4*)beta)[l + 64 * jj];
        wgr4[jj] = ((const f32x4*)wg)[l + 64 * jj];
        wgc4[jj] = ((const f32x4*)(wg + DDIM))[l + 64 * jj];
    }
    float wgt0 = wg[2 * DDIM + l], wgt1 = wg[2 * DDIM + l + 64];
    float tmpv = clampf(temperature[0], 0.5f, 5.f);
    float tinv = 1.f / (tmpv + 1e-4f);
    float bgv  = bg[0];

    // ---- per-row attention: wave w owns rows w*8 .. w*8+7, q never leaves regs ----
    for (int rr = 0; rr < 8; ++rr) {
        const int r = w * 8 + rr;
        const size_t R = (size_t)(R0 + r);
        const float* prow = prot + R * (5 * DDIM);

        f32x4 p4[5][2];                                   // 10 KB prototype stream
        #pragma unroll
        for (int k = 0; k < 5; ++k) {
            p4[k][0] = ((const f32x4*)(prow + k * DDIM))[l];
            p4[k][1] = ((const f32x4*)(prow + k * DDIM))[l + 64];
        }
        f32x4 rw4[2];                                     // fp32 raw re-read (L2-hot)
        #pragma unroll
        for (int jj = 0; jj < 2; ++jj) {
            f32x4 t = ((const f32x4*)(raw + R * DDIM))[l + 64 * jj];
            #pragma unroll
            for (int e2 = 0; e2 < 4; ++e2) rw4[jj][e2] = clampf(t[e2], -50.f, 50.f);
        }
        float t0 = timee[R * TDIM + l];
        float t1 = timee[R * TDIM + l + 64];

        // LN(C + bq) -> tanh -> q (in regs, float4 mapping)
        f32x4 v4[2];
        float s = 0.f, sq = 0.f;
        #pragma unroll
        for (int jj = 0; jj < 2; ++jj) {
            f32x4 cv = sm.c4[r * 128 + l + 64 * jj];
            cv += bq4[jj];
            v4[jj] = cv;
            #pragma unroll
            for (int e2 = 0; e2 < 4; ++e2) { s += cv[e2]; sq += cv[e2] * cv[e2]; }
        }
        s = wred_sum(s); sq = wred_sum(sq);
        float mu  = s * (1.f / 512.f);
        float var = sq * (1.f / 512.f) - mu * mu;
        float rs  = rsqrtf(fmaxf(var, 0.f) + 1e-6f);
        f32x4 q4[2];
        float qs = 0.f;
        #pragma unroll
        for (int jj = 0; jj < 2; ++jj)
            #pragma unroll
            for (int e2 = 0; e2 < 4; ++e2) {
                float y = (v4[jj][e2] - mu) * rs * g4[jj][e2] + b4[jj][e2];
                y = tanh_fast(y);
                q4[jj][e2] = y;
                qs += y * y;
            }
        qs = wred_sum(qs);
        float qinv = 1.f / fmaxf(sqrtf(qs), 1e-6f);

        // cosine sim vs 5 prototypes
        float sim[5];
        #pragma unroll
        for (int k = 0; k < 5; ++k) {
            float d = 0.f, pn = 0.f;
            #pragma unroll
            for (int jj = 0; jj < 2; ++jj)
                #pragma unroll
                for (int e2 = 0; e2 < 4; ++e2) {
                    float ps = clampf(p4[k][jj][e2], -20.f, 20.f);
                    d  += q4[jj][e2] * ps;
                    pn += ps * ps;
                }
            d = wred_sum(d); pn = wred_sum(pn);
            sim[k] = d * qinv * (1.f / fmaxf(sqrtf(pn), 1e-6f));
        }
        float mx = -1e30f;
        #pragma unroll
        for (int k = 0; k < 5; ++k) { sim[k] = clampf(sim[k], -15.f, 15.f) * tinv; mx = fmaxf(mx, sim[k]); }
        float ek[5], Z = 0.f;
        #pragma unroll
        for (int k = 0; k < 5; ++k) { ek[k] = __expf(sim[k] - mx); Z += ek[k]; }
        float zi = 1.f / Z;
        #pragma unroll
        for (int k = 0; k < 5; ++k) ek[k] = clampf(ek[k] * zi, 0.f, 1.f);

        f32x4 cand4[2];
        #pragma unroll
        for (int jj = 0; jj < 2; ++jj) {
            f32x4 c = (f32x4){0.f, 0.f, 0.f, 0.f};
            #pragma unroll
            for (int k = 0; k < 5; ++k) c += ek[k] * p4[k][jj];
            #pragma unroll
            for (int e2 = 0; e2 < 4; ++e2) cand4[jj][e2] = clampf(c[e2], -5.f, 5.f);
        }

        // gate
        float gp = 0.f;
        #pragma unroll
        for (int jj = 0; jj < 2; ++jj)
            #pragma unroll
            for (int e2 = 0; e2 < 4; ++e2) {
                gp += wgr4[jj][e2] * clampf(rw4[jj][e2],   -30.f, 30.f);
                gp += wgc4[jj][e2] * clampf(cand4[jj][e2], -30.f, 30.f);
            }
        gp += wgt0 * clampf(t0, -30.f, 30.f);
        gp += wgt1 * clampf(t1, -30.f, 30.f);
        gp = wred_sum(gp);
        float gl = clampf(gp + bgv, -10.f, 10.f);
        float g  = 1.f / (1.f + __expf(-gl));

        // residual blend + final LN + store
        f32x4 u4[2];
        s = 0.f; sq = 0.f;
        #pragma unroll
        for (int jj = 0; jj < 2; ++jj)
            #pragma unroll
            for (int e2 = 0; e2 < 4; ++e2) {
                float gated = (1.f - g) * rw4[jj][e2] + g * cand4[jj][e2];
                float u = 0.8f * rw4[jj][e2] + 0.2f * gated;
                u4[jj][e2] = u;
                s += u; sq += u * u;
            }
        s = wred_sum(s); sq = wred_sum(sq);
        mu  = s * (1.f / 512.f);
        var = sq * (1.f / 512.f) - mu * mu;
        rs  = rsqrtf(fmaxf(var, 0.f) + 1e-6f);
        #pragma unroll
        for (int jj = 0; jj < 2; ++jj) {
            f32x4 y4;
            #pragma unroll
            for (int e2 = 0; e2 < 4; ++e2)
                y4[e2] = clampf((u4[jj][e2] - mu) * rs * g4[jj][e2] + b4[jj][e2], -10.f, 10.f);
            ((f32x4*)(out + R * DDIM))[l + 64 * jj] = y4;
        }
    }
}

extern "C" void kernel_launch(void* const* d_in, const int* in_sizes, int n_in,
                              void* d_out, int out_size, void* d_ws, size_t ws_size,
                              hipStream_t stream) {
    const float* raw   = (const float*)d_in[0];
    // d_in[1] = node_features: unused by the reference
    const float* edge  = (const float*)d_in[2];
    const float* tim   = (const float*)d_in[3];
    const float* prot  = (const float*)d_in[4];
    const float* Wq    = (const float*)d_in[5];
    const float* bq    = (const float*)d_in[6];
    const float* Wg    = (const float*)d_in[7];
    const float* bg    = (const float*)d_in[8];
    const float* gamma = (const float*)d_in[9];
    const float* beta  = (const float*)d_in[10];
    const float* temp  = (const float*)d_in[11];
    float* out = (float*)d_out;
    unsigned short* wqb = (unsigned short*)d_ws;   // 458752 bf16 = 0.9 MB, swizzled

    k_conv_wq<<<224, 256, 0, stream>>>(Wq, wqb);   // 224*256 = 57344 bf16x8 fragments
    k_fused<<<NROWS / MT, 256, 0, stream>>>(raw, edge, tim, wqb, bq, Wg, bg,
                                            gamma, beta, prot, temp, out);
}